// Round 7
// baseline (815.286 us; speedup 1.0000x reference)
//
#include <hip/hip_runtime.h>

typedef short bf16x8 __attribute__((ext_vector_type(8)));
typedef float f32x4  __attribute__((ext_vector_type(4)));

__device__ __forceinline__ float bf2f(unsigned short h){
  union { unsigned int u; float f; } c; c.u = ((unsigned int)h) << 16; return c.f;
}
__device__ __forceinline__ unsigned short f2bf(float f){
  union { float f; unsigned int u; } c; c.f = f;
  unsigned int u = c.u;
  return (unsigned short)((u + 0x7fffu + ((u >> 16) & 1u)) >> 16);
}
__device__ __forceinline__ void gload_lds16(const void* g, void* l){
  __builtin_amdgcn_global_load_lds((const __attribute__((address_space(1))) unsigned int*)g,
                                   (__attribute__((address_space(3))) unsigned int*)l, 16, 0, 0);
}
__device__ __forceinline__ float lrelu(float x){ return x >= 0.f ? x : 0.01f * x; }

// ---------------- x (f32) -> bf16 ----------------
__global__ void cvt_f32_bf16(const float* __restrict__ x, unsigned short* __restrict__ o, int n4){
  int i = blockIdx.x * 256 + threadIdx.x;
  if (i >= n4) return;
  float4 v = ((const float4*)x)[i];
  ushort4 r; r.x = f2bf(v.x); r.y = f2bf(v.y); r.z = f2bf(v.z); r.w = f2bf(v.w);
  ((ushort4*)o)[i] = r;
}

// ---------------- W (K x N, f32) -> Wt (N x K, bf16) ----------------
__global__ void wt_kernel(const float* __restrict__ Wm, unsigned short* __restrict__ Wt, int K, int Nf){
  __shared__ float tile[32][33];
  int n0 = blockIdx.x * 32, k0 = blockIdx.y * 32;
  int tx = threadIdx.x, ty = threadIdx.y;
  for (int i = ty; i < 32; i += 8)
    tile[i][tx] = Wm[(size_t)(k0 + i) * Nf + n0 + tx];
  __syncthreads();
  for (int i = ty; i < 32; i += 8)
    Wt[(size_t)(n0 + i) * K + k0 + tx] = f2bf(tile[tx][i]);
}

// ---------------- counting sort of edges by dst ----------------
__global__ void hist_kernel(const int* __restrict__ dst, int* __restrict__ hist, int E){
  int e = blockIdx.x * 256 + threadIdx.x;
  if (e < E) atomicAdd(&hist[dst[e]], 1);
}

__global__ void scan_kernel(int* __restrict__ hist, int* __restrict__ cursor, int n, int total){
  __shared__ int partials[1024];
  const int CH = 20;
  int t = threadIdx.x;
  int base = t * CH;
  int local[CH];
  int s = 0;
  for (int i = 0; i < CH; i++){
    int idx = base + i;
    int v = (idx < n) ? hist[idx] : 0;
    local[i] = s; s += v;
  }
  partials[t] = s;
  __syncthreads();
  for (int off = 1; off < 1024; off <<= 1){
    int v = (t >= off) ? partials[t - off] : 0;
    __syncthreads();
    if (t >= off) partials[t] += v;
    __syncthreads();
  }
  int pre = (t == 0) ? 0 : partials[t - 1];
  for (int i = 0; i < CH; i++){
    int idx = base + i;
    if (idx < n){ int v = pre + local[i]; hist[idx] = v; cursor[idx] = v; }
  }
  if (t == 0){ hist[n] = total; }
}

__global__ void scatter_kernel(const int* __restrict__ src, const int* __restrict__ dst,
                               const float* __restrict__ ew, int* __restrict__ cursor,
                               int* __restrict__ so, float* __restrict__ eo, int E){
  int e = blockIdx.x * 256 + threadIdx.x;
  if (e >= E) return;
  int d = dst[e];
  int p = atomicAdd(&cursor[d], 1);
  so[p] = src[e]; eo[p] = ew[e];
}

// ---------------- GEMM (4-wave 128x128, XCD-chunked swizzle) ----------------
// 1-D grid, nwg = Mt*Nt. m204 bijective chunk swizzle: each XCD gets a
// contiguous wgid range; wgid%Nt fastest -> blocks sharing an A-panel are
// consecutive on the SAME XCD's L2.
__global__ __launch_bounds__(256) void gemm_bf16(const unsigned short* __restrict__ A,
                                                 const unsigned short* __restrict__ Bt,
                                                 unsigned short* __restrict__ C,
                                                 int Nf, int K, int Nt){
  __shared__ unsigned short lsA[128 * 64];
  __shared__ unsigned short lsB[128 * 64];
  const int nwg = gridDim.x;
  const int orig = blockIdx.x;
  const int q = nwg >> 3, r = nwg & 7;
  const int xcd = orig & 7, idx = orig >> 3;
  const int wgid = (xcd < r ? xcd * (q + 1) : r * (q + 1) + (xcd - r) * q) + idx;
  const int mt = wgid / Nt, nt = wgid % Nt;

  const int tid = threadIdx.x;
  const int wave = tid >> 6, lane = tid & 63;
  const int wr = wave >> 1, wc = wave & 1;
  const size_t tm = (size_t)mt * 128, tn = (size_t)nt * 128;

  f32x4 acc[4][4] = {};

  const int lrow = lane >> 3;
  const int lcol = (lane & 7) * 8;
  const unsigned short* Ab = A  + (tm + wave * 32 + lrow) * (size_t)K + lcol;
  const unsigned short* Bb = Bt + (tn + wave * 32 + lrow) * (size_t)K + lcol;
  unsigned short* lA0 = &lsA[(wave * 32) * 64];
  unsigned short* lB0 = &lsB[(wave * 32) * 64];

  for (int k0 = 0; k0 < K; k0 += 64){
    #pragma unroll
    for (int s = 0; s < 4; s++){
      gload_lds16(Ab + (size_t)s * 8 * K + k0, lA0 + s * 8 * 64);
      gload_lds16(Bb + (size_t)s * 8 * K + k0, lB0 + s * 8 * 64);
    }
    __syncthreads();
    #pragma unroll
    for (int kk = 0; kk < 2; kk++){
      bf16x8 af[4], bfr[4];
      #pragma unroll
      for (int m = 0; m < 4; m++)
        af[m] = *(const bf16x8*)&lsA[(wr * 64 + m * 16 + (lane & 15)) * 64 + kk * 32 + (lane >> 4) * 8];
      #pragma unroll
      for (int n = 0; n < 4; n++)
        bfr[n] = *(const bf16x8*)&lsB[(wc * 64 + n * 16 + (lane & 15)) * 64 + kk * 32 + (lane >> 4) * 8];
      #pragma unroll
      for (int m = 0; m < 4; m++)
        #pragma unroll
        for (int n = 0; n < 4; n++)
          acc[m][n] = __builtin_amdgcn_mfma_f32_16x16x32_bf16(af[m], bfr[n], acc[m][n], 0, 0, 0);
    }
    __syncthreads();
  }
  #pragma unroll
  for (int m = 0; m < 4; m++)
    #pragma unroll
    for (int n = 0; n < 4; n++)
      #pragma unroll
      for (int j = 0; j < 4; j++){
        size_t row = tm + wr * 64 + m * 16 + (lane >> 4) * 4 + j;
        size_t col = tn + wc * 64 + n * 16 + (lane & 15);
        C[row * Nf + col] = f2bf(acc[m][n][j]);
      }
}

// ---------------- panelized CSR aggregation (panel -> XCD pinning) ----------------
// F split into 8 panels of C*8 cols; panel = flatBlock % 8 so (assuming
// round-robin dispatch) each panel's gathers stay in ONE XCD's L2
// (panel footprint: 20000*C*16 bytes <= 3.2 MB < 4 MiB).
template<int F, int C, int G, int NPB>
__global__ __launch_bounds__(C * G * NPB)
void agg_panel(const unsigned short* __restrict__ H,
               const int* __restrict__ rp,
               const int* __restrict__ srcs,
               const float* __restrict__ ews,
               float* __restrict__ AGG, int Nnodes){
  const int flat = blockIdx.x;
  const int panel = flat & 7;
  const int ngrp = flat >> 3;
  const int t = threadIdx.x;
  const int c = t % C;
  const int g = (t / C) % G;
  const int ni = t / (C * G);
  const int node = ngrp * NPB + ni;
  const bool valid = (node < Nnodes);
  const size_t coff = (size_t)panel * (C * 8) + (size_t)c * 8;

  int e0 = 0, e1 = 0;
  if (valid){ e0 = rp[node]; e1 = rp[node + 1]; }

  float acc[8] = {0.f,0.f,0.f,0.f,0.f,0.f,0.f,0.f};
  int e = e0 + g;
  for (; e + G < e1; e += 2 * G){
    int s0 = srcs[e];     float w0 = ews[e];
    int s1 = srcs[e + G]; float w1 = ews[e + G];
    bf16x8 v0 = *(const bf16x8*)&H[(size_t)s0 * F + coff];
    bf16x8 v1 = *(const bf16x8*)&H[(size_t)s1 * F + coff];
    #pragma unroll
    for (int j = 0; j < 8; j++) acc[j] += w0 * bf2f((unsigned short)v0[j]);
    #pragma unroll
    for (int j = 0; j < 8; j++) acc[j] += w1 * bf2f((unsigned short)v1[j]);
  }
  if (e < e1){
    int s0 = srcs[e]; float w0 = ews[e];
    bf16x8 v0 = *(const bf16x8*)&H[(size_t)s0 * F + coff];
    #pragma unroll
    for (int j = 0; j < 8; j++) acc[j] += w0 * bf2f((unsigned short)v0[j]);
  }

  __shared__ float red[NPB * G * C * 8];
  if (g > 0){
    #pragma unroll
    for (int j = 0; j < 8; j++) red[((ni * G + g) * C + c) * 8 + j] = acc[j];
  }
  __syncthreads();
  if (g == 0 && valid){
    #pragma unroll
    for (int gg = 1; gg < G; gg++)
      #pragma unroll
      for (int j = 0; j < 8; j++) acc[j] += red[((ni * G + gg) * C + c) * 8 + j];
    float* orow = AGG + (size_t)node * F + coff;
    *(float4*)(orow)     = *(float4*)&acc[0];
    *(float4*)(orow + 4) = *(float4*)&acc[4];
  }
}

// ---------------- column stats (float4) ----------------
__global__ void stats_kernel_v(const float* __restrict__ AGG, float* __restrict__ sum,
                               float* __restrict__ sumsq, int F){
  int nf4 = F >> 2;
  int f4 = blockIdx.x * 256 + threadIdx.x;
  if (f4 >= nf4) return;
  const float4* p = (const float4*)(AGG + (size_t)blockIdx.y * 500 * F) + f4;
  float4 s = {0.f,0.f,0.f,0.f}, q = {0.f,0.f,0.f,0.f};
  for (int r = 0; r < 500; r++){
    float4 v = p[(size_t)r * nf4];
    s.x += v.x; s.y += v.y; s.z += v.z; s.w += v.w;
    q.x += v.x*v.x; q.y += v.y*v.y; q.z += v.z*v.z; q.w += v.w*v.w;
  }
  atomicAdd(&sum[f4*4+0], s.x); atomicAdd(&sum[f4*4+1], s.y);
  atomicAdd(&sum[f4*4+2], s.z); atomicAdd(&sum[f4*4+3], s.w);
  atomicAdd(&sumsq[f4*4+0], q.x); atomicAdd(&sumsq[f4*4+1], q.y);
  atomicAdd(&sumsq[f4*4+2], q.z); atomicAdd(&sumsq[f4*4+3], q.w);
}

// ---------------- BN + LeakyReLU + cast, flat grid (all lanes active) ----------------
__global__ void norm_kernel_v2(const float* __restrict__ AGG, const float* __restrict__ sum,
                               const float* __restrict__ sumsq, const float* __restrict__ gw,
                               const float* __restrict__ bw, unsigned short* __restrict__ OUT,
                               int nf4, int total4){
  int i = blockIdx.x * 256 + threadIdx.x;
  if (i >= total4) return;
  int f4 = i % nf4;
  const float inv = 1.0f / 20000.0f;
  float4 s = ((const float4*)sum)[f4];
  float4 q = ((const float4*)sumsq)[f4];
  float4 g = ((const float4*)gw)[f4];
  float4 b = ((const float4*)bw)[f4];
  float4 a = ((const float4*)AGG)[i];
  ushort4 o;
  { float m = s.x * inv, v = fmaxf(q.x * inv - m * m, 0.f);
    o.x = f2bf(lrelu((a.x - m) * rsqrtf(v + 1e-5f) * g.x + b.x)); }
  { float m = s.y * inv, v = fmaxf(q.y * inv - m * m, 0.f);
    o.y = f2bf(lrelu((a.y - m) * rsqrtf(v + 1e-5f) * g.y + b.y)); }
  { float m = s.z * inv, v = fmaxf(q.z * inv - m * m, 0.f);
    o.z = f2bf(lrelu((a.z - m) * rsqrtf(v + 1e-5f) * g.z + b.z)); }
  { float m = s.w * inv, v = fmaxf(q.w * inv - m * m, 0.f);
    o.w = f2bf(lrelu((a.w - m) * rsqrtf(v + 1e-5f) * g.w + b.w)); }
  ((ushort4*)OUT)[i] = o;
}

// ---------------- graph boundaries in sorted batch ----------------
__global__ void bounds_kernel(const int* __restrict__ batch, int* __restrict__ gstart, int n){
  int g = threadIdx.x;
  if (g > 256) return;
  int lo = 0, hi = n;
  while (lo < hi){ int mid = (lo + hi) >> 1; if (batch[mid] < g) lo = mid + 1; else hi = mid; }
  gstart[g] = lo;
}

// ---------------- pooling (vectorized) ----------------
__global__ __launch_bounds__(256) void pool_kernel_v(const unsigned short* __restrict__ A1,
                                                     const int* __restrict__ gstart,
                                                     float* __restrict__ pooled){
  int gph = blockIdx.x;
  int t = threadIdx.x;
  int c = t & 31, g = t >> 5;
  int r0 = gstart[gph], r1 = gstart[gph + 1];
  float acc[8] = {0.f,0.f,0.f,0.f,0.f,0.f,0.f,0.f};
  for (int r = r0 + g; r < r1; r += 8){
    bf16x8 v = *(const bf16x8*)&A1[(size_t)r * 256 + c * 8];
    #pragma unroll
    for (int j = 0; j < 8; j++) acc[j] += bf2f((unsigned short)v[j]);
  }
  __shared__ float red[8][256];
  if (g > 0){
    #pragma unroll
    for (int j = 0; j < 8; j++) red[g][c * 8 + j] = acc[j];
  }
  __syncthreads();
  if (g == 0){
    #pragma unroll
    for (int gg = 1; gg < 8; gg++)
      #pragma unroll
      for (int j = 0; j < 8; j++) acc[j] += red[gg][c * 8 + j];
    #pragma unroll
    for (int j = 0; j < 8; j++) pooled[gph * 256 + c * 8 + j] = acc[j];
  }
}

// ---------------- fused FC head: 256->128->64->2 with lrelu ----------------
__global__ void fc_kernel(const float* __restrict__ pooled,
                          const float* __restrict__ Wf1, const float* __restrict__ bf1,
                          const float* __restrict__ Wf2, const float* __restrict__ bf2,
                          const float* __restrict__ Wf3, const float* __restrict__ bf3,
                          float* __restrict__ out){
  int g = blockIdx.x, t = threadIdx.x; // 128 threads
  __shared__ float p0[256], p1[128], p2[64];
  p0[t] = pooled[g * 256 + t];
  p0[t + 128] = pooled[g * 256 + t + 128];
  __syncthreads();
  float a = bf1[t];
  for (int k = 0; k < 256; k++) a += p0[k] * Wf1[k * 128 + t];
  p1[t] = lrelu(a);
  __syncthreads();
  if (t < 64){
    float a2 = bf2[t];
    for (int k = 0; k < 128; k++) a2 += p1[k] * Wf2[k * 64 + t];
    p2[t] = lrelu(a2);
  }
  __syncthreads();
  if (t < 2){
    float a3 = bf3[t];
    for (int k = 0; k < 64; k++) a3 += p2[k] * Wf3[k * 2 + t];
    out[g * 2 + t] = lrelu(a3);
  }
}

extern "C" void kernel_launch(void* const* d_in, const int* in_sizes, int n_in,
                              void* d_out, int out_size, void* d_ws, size_t ws_size,
                              hipStream_t stream){
  const int N = 20000, E = 320000;
  const float* x     = (const float*)d_in[0];
  const int*   ei    = (const int*)d_in[1];
  const float* ew    = (const float*)d_in[2];
  const int*   batch = (const int*)d_in[3];
  const float* W[4]  = {(const float*)d_in[4], (const float*)d_in[8], (const float*)d_in[12], (const float*)d_in[16]};
  const float* gw[4] = {(const float*)d_in[6], (const float*)d_in[10], (const float*)d_in[14], (const float*)d_in[18]};
  const float* bw[4] = {(const float*)d_in[7], (const float*)d_in[11], (const float*)d_in[15], (const float*)d_in[19]};
  const float* Wf1 = (const float*)d_in[20]; const float* bf1 = (const float*)d_in[21];
  const float* Wf2 = (const float*)d_in[22]; const float* bf2 = (const float*)d_in[23];
  const float* Wf3 = (const float*)d_in[24]; const float* bf3 = (const float*)d_in[25];

  const int Kd[4] = {1280, 640, 512, 256};
  const int Nd[4] = {640, 512, 256, 256};

  // workspace carve (XB aliases AGG: XB dead after layer-1 GEMM)
  char* w = (char*)d_ws;
  unsigned short* XB = (unsigned short*)w;
  float* AGG = (float*)w;                 w += 51445760;  // 20096*1280*2
  unsigned short* H  = (unsigned short*)w; w += 25722880; // 20096*640*2
  unsigned short* A1 = (unsigned short*)w; w += 25722880; // 20096*640*2
  unsigned short* WT = (unsigned short*)w; w += 1638400;  // 1280*640*2
  int*   hist   = (int*)w;   w += 80128;  // 20001 ints (becomes row_ptr)
  int*   cursor = (int*)w;   w += 80128;
  int*   srcs   = (int*)w;   w += 1280000;
  float* ews    = (float*)w; w += 1280000;
  float* sum    = (float*)w; w += 2560;
  float* sumsq  = (float*)w; w += 2560;   // adjacent to sum: one memset
  int*   gstart = (int*)w;   w += 1280;
  float* pooled = (float*)w; w += 262144;
  (void)ws_size; (void)n_in; (void)in_sizes; (void)out_size;

  cvt_f32_bf16<<<(N * 1280 / 4 + 255) / 256, 256, 0, stream>>>(x, XB, N * 1280 / 4);

  hipMemsetAsync(hist, 0, 80128, stream);
  hist_kernel<<<E / 256, 256, 0, stream>>>(ei + E, hist, E);
  scan_kernel<<<1, 1024, 0, stream>>>(hist, cursor, N, E);
  scatter_kernel<<<E / 256, 256, 0, stream>>>(ei, ei + E, ew, cursor, srcs, ews, E);

  bounds_kernel<<<1, 320, 0, stream>>>(batch, gstart, N);

  const unsigned short* in = XB;
  for (int l = 0; l < 4; l++){
    int K = Kd[l], Nf = Nd[l];
    int Nt = Nf / 128;
    wt_kernel<<<dim3(Nf / 32, K / 32), dim3(32, 8), 0, stream>>>(W[l], WT, K, Nf);
    gemm_bf16<<<157 * Nt, 256, 0, stream>>>(in, WT, H, Nf, K, Nt);
    if (Nf == 640)      agg_panel<640, 10, 8, 3><<<((N + 2) / 3) * 8, 240, 0, stream>>>(H, hist, srcs, ews, AGG, N);
    else if (Nf == 512) agg_panel<512,  8, 8, 4><<<(N / 4) * 8, 256, 0, stream>>>(H, hist, srcs, ews, AGG, N);
    else                agg_panel<256,  4, 8, 8><<<(N / 8) * 8, 256, 0, stream>>>(H, hist, srcs, ews, AGG, N);
    hipMemsetAsync(sum, 0, 5120, stream);
    stats_kernel_v<<<dim3((Nf / 4 + 255) / 256, 40), 256, 0, stream>>>(AGG, sum, sumsq, Nf);
    int total4 = N * (Nf >> 2);
    norm_kernel_v2<<<(total4 + 255) / 256, 256, 0, stream>>>(AGG, sum, sumsq, gw[l], bw[l], A1, Nf >> 2, total4);
    in = A1;
  }

  pool_kernel_v<<<256, 256, 0, stream>>>(A1, gstart, pooled);
  fc_kernel<<<256, 128, 0, stream>>>(pooled, Wf1, bf1, Wf2, bf2, Wf3, bf3, (float*)d_out);
}

// Round 9
// 780.861 us; speedup vs baseline: 1.0441x; 1.0441x over previous
//
#include <hip/hip_runtime.h>

typedef short bf16x8 __attribute__((ext_vector_type(8)));
typedef float f32x4  __attribute__((ext_vector_type(4)));

__device__ __forceinline__ float bf2f(unsigned short h){
  union { unsigned int u; float f; } c; c.u = ((unsigned int)h) << 16; return c.f;
}
__device__ __forceinline__ unsigned short f2bf(float f){
  union { float f; unsigned int u; } c; c.f = f;
  unsigned int u = c.u;
  return (unsigned short)((u + 0x7fffu + ((u >> 16) & 1u)) >> 16);
}
__device__ __forceinline__ void gload_lds16(const void* g, void* l){
  __builtin_amdgcn_global_load_lds((const __attribute__((address_space(1))) unsigned int*)g,
                                   (__attribute__((address_space(3))) unsigned int*)l, 16, 0, 0);
}
__device__ __forceinline__ float lrelu(float x){ return x >= 0.f ? x : 0.01f * x; }
// two bf16 packed in a dword -> two f32 fma into accumulators
__device__ __forceinline__ void acc2(float& a0, float& a1, unsigned int u, float w){
  float lo = __uint_as_float(u << 16);
  float hi = __uint_as_float(u & 0xffff0000u);
  a0 = fmaf(lo, w, a0); a1 = fmaf(hi, w, a1);
}

// ---------------- x (f32) -> bf16 ----------------
__global__ void cvt_f32_bf16(const float* __restrict__ x, unsigned short* __restrict__ o, int n4){
  int i = blockIdx.x * 256 + threadIdx.x;
  if (i >= n4) return;
  float4 v = ((const float4*)x)[i];
  ushort4 r; r.x = f2bf(v.x); r.y = f2bf(v.y); r.z = f2bf(v.z); r.w = f2bf(v.w);
  ((ushort4*)o)[i] = r;
}

// ---------------- W (K x N, f32) -> Wt (N x K, bf16) ----------------
__global__ void wt_kernel(const float* __restrict__ Wm, unsigned short* __restrict__ Wt, int K, int Nf){
  __shared__ float tile[32][33];
  int n0 = blockIdx.x * 32, k0 = blockIdx.y * 32;
  int tx = threadIdx.x, ty = threadIdx.y;
  for (int i = ty; i < 32; i += 8)
    tile[i][tx] = Wm[(size_t)(k0 + i) * Nf + n0 + tx];
  __syncthreads();
  for (int i = ty; i < 32; i += 8)
    Wt[(size_t)(n0 + i) * K + k0 + tx] = f2bf(tile[tx][i]);
}

// ---------------- counting sort of edges by dst ----------------
__global__ void hist_kernel(const int* __restrict__ dst, int* __restrict__ hist, int E){
  int e = blockIdx.x * 256 + threadIdx.x;
  if (e < E) atomicAdd(&hist[dst[e]], 1);
}

__global__ void scan_kernel(int* __restrict__ hist, int* __restrict__ cursor, int n, int total){
  __shared__ int partials[1024];
  const int CH = 20;
  int t = threadIdx.x;
  int base = t * CH;
  int local[CH];
  int s = 0;
  for (int i = 0; i < CH; i++){
    int idx = base + i;
    int v = (idx < n) ? hist[idx] : 0;
    local[i] = s; s += v;
  }
  partials[t] = s;
  __syncthreads();
  for (int off = 1; off < 1024; off <<= 1){
    int v = (t >= off) ? partials[t - off] : 0;
    __syncthreads();
    if (t >= off) partials[t] += v;
    __syncthreads();
  }
  int pre = (t == 0) ? 0 : partials[t - 1];
  for (int i = 0; i < CH; i++){
    int idx = base + i;
    if (idx < n){ int v = pre + local[i]; hist[idx] = v; cursor[idx] = v; }
  }
  if (t == 0){ hist[n] = total; }
}

__global__ void scatter_kernel(const int* __restrict__ src, const int* __restrict__ dst,
                               const float* __restrict__ ew, int* __restrict__ cursor,
                               int* __restrict__ so, float* __restrict__ eo, int E){
  int e = blockIdx.x * 256 + threadIdx.x;
  if (e >= E) return;
  int d = dst[e];
  int p = atomicAdd(&cursor[d], 1);
  so[p] = src[e]; eo[p] = ew[e];
}

// ---------------- GEMM (4-wave 128x128, XCD-chunked swizzle) ----------------
__global__ __launch_bounds__(256) void gemm_bf16(const unsigned short* __restrict__ A,
                                                 const unsigned short* __restrict__ Bt,
                                                 unsigned short* __restrict__ C,
                                                 int Nf, int K, int Nt){
  __shared__ unsigned short lsA[128 * 64];
  __shared__ unsigned short lsB[128 * 64];
  const int nwg = gridDim.x;
  const int orig = blockIdx.x;
  const int q = nwg >> 3, r = nwg & 7;
  const int xcd = orig & 7, idx = orig >> 3;
  const int wgid = (xcd < r ? xcd * (q + 1) : r * (q + 1) + (xcd - r) * q) + idx;
  const int mt = wgid / Nt, nt = wgid % Nt;

  const int tid = threadIdx.x;
  const int wave = tid >> 6, lane = tid & 63;
  const int wr = wave >> 1, wc = wave & 1;
  const size_t tm = (size_t)mt * 128, tn = (size_t)nt * 128;

  f32x4 acc[4][4] = {};

  const int lrow = lane >> 3;
  const int lcol = (lane & 7) * 8;
  const unsigned short* Ab = A  + (tm + wave * 32 + lrow) * (size_t)K + lcol;
  const unsigned short* Bb = Bt + (tn + wave * 32 + lrow) * (size_t)K + lcol;
  unsigned short* lA0 = &lsA[(wave * 32) * 64];
  unsigned short* lB0 = &lsB[(wave * 32) * 64];

  for (int k0 = 0; k0 < K; k0 += 64){
    #pragma unroll
    for (int s = 0; s < 4; s++){
      gload_lds16(Ab + (size_t)s * 8 * K + k0, lA0 + s * 8 * 64);
      gload_lds16(Bb + (size_t)s * 8 * K + k0, lB0 + s * 8 * 64);
    }
    __syncthreads();
    #pragma unroll
    for (int kk = 0; kk < 2; kk++){
      bf16x8 af[4], bfr[4];
      #pragma unroll
      for (int m = 0; m < 4; m++)
        af[m] = *(const bf16x8*)&lsA[(wr * 64 + m * 16 + (lane & 15)) * 64 + kk * 32 + (lane >> 4) * 8];
      #pragma unroll
      for (int n = 0; n < 4; n++)
        bfr[n] = *(const bf16x8*)&lsB[(wc * 64 + n * 16 + (lane & 15)) * 64 + kk * 32 + (lane >> 4) * 8];
      #pragma unroll
      for (int m = 0; m < 4; m++)
        #pragma unroll
        for (int n = 0; n < 4; n++)
          acc[m][n] = __builtin_amdgcn_mfma_f32_16x16x32_bf16(af[m], bfr[n], acc[m][n], 0, 0, 0);
    }
    __syncthreads();
  }
  #pragma unroll
  for (int m = 0; m < 4; m++)
    #pragma unroll
    for (int n = 0; n < 4; n++)
      #pragma unroll
      for (int j = 0; j < 4; j++){
        size_t row = tm + wr * 64 + m * 16 + (lane >> 4) * 4 + j;
        size_t col = tn + wc * 64 + n * 16 + (lane & 15);
        C[row * Nf + col] = f2bf(acc[m][n][j]);
      }
}

// ---------------- CSR aggregation: one WAVE per node, whole-row coalesced ----------------
// Row of F bf16 = F/2 dwords, split across 64 lanes. Per edge: one or two
// vector loads covering the ENTIRE row contiguously (512B/1KB/1.25KB burst).
// Edge loop is wave-uniform (readfirstlane) -> srcs/ews scalarize to s_loads.
// No groups -> no divergence, no LDS reduction. 4 waves (nodes) per block.
template<int F>
__global__ __launch_bounds__(256)
void agg_row(const unsigned short* __restrict__ H,
             const int* __restrict__ rp,
             const int* __restrict__ srcs,
             const float* __restrict__ ews,
             float* __restrict__ AGG, int Nnodes){
  const int wv = threadIdx.x >> 6, ln = threadIdx.x & 63;
  int node = blockIdx.x * 4 + wv;
  if (node >= Nnodes) return;
  node = __builtin_amdgcn_readfirstlane(node);
  const int e0 = rp[node], e1 = rp[node + 1];
  const unsigned int* Hd = (const unsigned int*)H;
  constexpr int RD = F / 2;   // dwords per row

  float a0=0.f,a1=0.f,a2=0.f,a3=0.f,a4=0.f,a5=0.f,a6=0.f,a7=0.f,a8=0.f,a9=0.f;

  #define AGG_BODY(E) {                                            \
    int s_ = srcs[E]; float w_ = ews[E];                           \
    const unsigned int* row_ = Hd + (size_t)s_ * RD;               \
    if constexpr (F == 256){                                       \
      uint2 v_ = *(const uint2*)(row_ + ln * 2);                   \
      acc2(a0,a1,v_.x,w_); acc2(a2,a3,v_.y,w_);                    \
    } else if constexpr (F == 512){                                \
      uint4 v_ = *(const uint4*)(row_ + ln * 4);                   \
      acc2(a0,a1,v_.x,w_); acc2(a2,a3,v_.y,w_);                    \
      acc2(a4,a5,v_.z,w_); acc2(a6,a7,v_.w,w_);                    \
    } else {                                                       \
      uint4 v_ = *(const uint4*)(row_ + ln * 4);                   \
      unsigned int v2_ = row_[256 + ln];                           \
      acc2(a0,a1,v_.x,w_); acc2(a2,a3,v_.y,w_);                    \
      acc2(a4,a5,v_.z,w_); acc2(a6,a7,v_.w,w_);                    \
      acc2(a8,a9,v2_,w_);                                          \
    }                                                              \
  }

  int e = e0;
  for (; e + 1 < e1; e += 2){ AGG_BODY(e); AGG_BODY(e + 1); }
  if (e < e1) AGG_BODY(e);
  #undef AGG_BODY

  float* orow = AGG + (size_t)node * F;
  if constexpr (F == 256){
    float4 o = {a0, a1, a2, a3};
    *(float4*)(orow + ln * 4) = o;
  } else if constexpr (F == 512){
    float4 oA = {a0, a1, a2, a3}, oB = {a4, a5, a6, a7};
    *(float4*)(orow + ln * 8) = oA;
    *(float4*)(orow + ln * 8 + 4) = oB;
  } else {
    float4 oA = {a0, a1, a2, a3}, oB = {a4, a5, a6, a7};
    *(float4*)(orow + ln * 8) = oA;
    *(float4*)(orow + ln * 8 + 4) = oB;
    float2 oC = {a8, a9};
    *(float2*)(orow + 512 + ln * 2) = oC;
  }
}

// ---------------- column stats (float4) ----------------
__global__ void stats_kernel_v(const float* __restrict__ AGG, float* __restrict__ sum,
                               float* __restrict__ sumsq, int F){
  int nf4 = F >> 2;
  int f4 = blockIdx.x * 256 + threadIdx.x;
  if (f4 >= nf4) return;
  const float4* p = (const float4*)(AGG + (size_t)blockIdx.y * 500 * F) + f4;
  float4 s = {0.f,0.f,0.f,0.f}, q = {0.f,0.f,0.f,0.f};
  for (int r = 0; r < 500; r++){
    float4 v = p[(size_t)r * nf4];
    s.x += v.x; s.y += v.y; s.z += v.z; s.w += v.w;
    q.x += v.x*v.x; q.y += v.y*v.y; q.z += v.z*v.z; q.w += v.w*v.w;
  }
  atomicAdd(&sum[f4*4+0], s.x); atomicAdd(&sum[f4*4+1], s.y);
  atomicAdd(&sum[f4*4+2], s.z); atomicAdd(&sum[f4*4+3], s.w);
  atomicAdd(&sumsq[f4*4+0], q.x); atomicAdd(&sumsq[f4*4+1], q.y);
  atomicAdd(&sumsq[f4*4+2], q.z); atomicAdd(&sumsq[f4*4+3], q.w);
}

// ---------------- BN + LeakyReLU + cast, flat grid ----------------
__global__ void norm_kernel_v2(const float* __restrict__ AGG, const float* __restrict__ sum,
                               const float* __restrict__ sumsq, const float* __restrict__ gw,
                               const float* __restrict__ bw, unsigned short* __restrict__ OUT,
                               int nf4, int total4){
  int i = blockIdx.x * 256 + threadIdx.x;
  if (i >= total4) return;
  int f4 = i % nf4;
  const float inv = 1.0f / 20000.0f;
  float4 s = ((const float4*)sum)[f4];
  float4 q = ((const float4*)sumsq)[f4];
  float4 g = ((const float4*)gw)[f4];
  float4 b = ((const float4*)bw)[f4];
  float4 a = ((const float4*)AGG)[i];
  ushort4 o;
  { float m = s.x * inv, v = fmaxf(q.x * inv - m * m, 0.f);
    o.x = f2bf(lrelu((a.x - m) * rsqrtf(v + 1e-5f) * g.x + b.x)); }
  { float m = s.y * inv, v = fmaxf(q.y * inv - m * m, 0.f);
    o.y = f2bf(lrelu((a.y - m) * rsqrtf(v + 1e-5f) * g.y + b.y)); }
  { float m = s.z * inv, v = fmaxf(q.z * inv - m * m, 0.f);
    o.z = f2bf(lrelu((a.z - m) * rsqrtf(v + 1e-5f) * g.z + b.z)); }
  { float m = s.w * inv, v = fmaxf(q.w * inv - m * m, 0.f);
    o.w = f2bf(lrelu((a.w - m) * rsqrtf(v + 1e-5f) * g.w + b.w)); }
  ((ushort4*)OUT)[i] = o;
}

// ---------------- graph boundaries in sorted batch ----------------
__global__ void bounds_kernel(const int* __restrict__ batch, int* __restrict__ gstart, int n){
  int g = threadIdx.x;
  if (g > 256) return;
  int lo = 0, hi = n;
  while (lo < hi){ int mid = (lo + hi) >> 1; if (batch[mid] < g) lo = mid + 1; else hi = mid; }
  gstart[g] = lo;
}

// ---------------- pooling (vectorized) ----------------
__global__ __launch_bounds__(256) void pool_kernel_v(const unsigned short* __restrict__ A1,
                                                     const int* __restrict__ gstart,
                                                     float* __restrict__ pooled){
  int gph = blockIdx.x;
  int t = threadIdx.x;
  int c = t & 31, g = t >> 5;
  int r0 = gstart[gph], r1 = gstart[gph + 1];
  float acc[8] = {0.f,0.f,0.f,0.f,0.f,0.f,0.f,0.f};
  for (int r = r0 + g; r < r1; r += 8){
    bf16x8 v = *(const bf16x8*)&A1[(size_t)r * 256 + c * 8];
    #pragma unroll
    for (int j = 0; j < 8; j++) acc[j] += bf2f((unsigned short)v[j]);
  }
  __shared__ float red[8][256];
  if (g > 0){
    #pragma unroll
    for (int j = 0; j < 8; j++) red[g][c * 8 + j] = acc[j];
  }
  __syncthreads();
  if (g == 0){
    #pragma unroll
    for (int gg = 1; gg < 8; gg++)
      #pragma unroll
      for (int j = 0; j < 8; j++) acc[j] += red[gg][c * 8 + j];
    #pragma unroll
    for (int j = 0; j < 8; j++) pooled[gph * 256 + c * 8 + j] = acc[j];
  }
}

// ---------------- fused FC head: 256->128->64->2 with lrelu ----------------
__global__ void fc_kernel(const float* __restrict__ pooled,
                          const float* __restrict__ Wf1, const float* __restrict__ bf1,
                          const float* __restrict__ Wf2, const float* __restrict__ bf2,
                          const float* __restrict__ Wf3, const float* __restrict__ bf3,
                          float* __restrict__ out){
  int g = blockIdx.x, t = threadIdx.x; // 128 threads
  __shared__ float p0[256], p1[128], p2[64];
  p0[t] = pooled[g * 256 + t];
  p0[t + 128] = pooled[g * 256 + t + 128];
  __syncthreads();
  float a = bf1[t];
  for (int k = 0; k < 256; k++) a += p0[k] * Wf1[k * 128 + t];
  p1[t] = lrelu(a);
  __syncthreads();
  if (t < 64){
    float a2 = bf2[t];
    for (int k = 0; k < 128; k++) a2 += p1[k] * Wf2[k * 64 + t];
    p2[t] = lrelu(a2);
  }
  __syncthreads();
  if (t < 2){
    float a3 = bf3[t];
    for (int k = 0; k < 64; k++) a3 += p2[k] * Wf3[k * 2 + t];
    out[g * 2 + t] = lrelu(a3);
  }
}

extern "C" void kernel_launch(void* const* d_in, const int* in_sizes, int n_in,
                              void* d_out, int out_size, void* d_ws, size_t ws_size,
                              hipStream_t stream){
  const int N = 20000, E = 320000;
  const float* x     = (const float*)d_in[0];
  const int*   ei    = (const int*)d_in[1];
  const float* ew    = (const float*)d_in[2];
  const int*   batch = (const int*)d_in[3];
  const float* W[4]  = {(const float*)d_in[4], (const float*)d_in[8], (const float*)d_in[12], (const float*)d_in[16]};
  const float* gw[4] = {(const float*)d_in[6], (const float*)d_in[10], (const float*)d_in[14], (const float*)d_in[18]};
  const float* bw[4] = {(const float*)d_in[7], (const float*)d_in[11], (const float*)d_in[15], (const float*)d_in[19]};
  const float* Wf1 = (const float*)d_in[20]; const float* bf1 = (const float*)d_in[21];
  const float* Wf2 = (const float*)d_in[22]; const float* bf2 = (const float*)d_in[23];
  const float* Wf3 = (const float*)d_in[24]; const float* bf3 = (const float*)d_in[25];

  const int Kd[4] = {1280, 640, 512, 256};
  const int Nd[4] = {640, 512, 256, 256};

  // workspace carve (XB aliases AGG: XB dead after layer-1 GEMM)
  char* w = (char*)d_ws;
  unsigned short* XB = (unsigned short*)w;
  float* AGG = (float*)w;                 w += 51445760;  // 20096*1280*2
  unsigned short* H  = (unsigned short*)w; w += 25722880; // 20096*640*2
  unsigned short* A1 = (unsigned short*)w; w += 25722880; // 20096*640*2
  unsigned short* WT = (unsigned short*)w; w += 1638400;  // 1280*640*2
  int*   hist   = (int*)w;   w += 80128;  // 20001 ints (becomes row_ptr)
  int*   cursor = (int*)w;   w += 80128;
  int*   srcs   = (int*)w;   w += 1280000;
  float* ews    = (float*)w; w += 1280000;
  float* sum    = (float*)w; w += 2560;
  float* sumsq  = (float*)w; w += 2560;   // adjacent to sum: one memset
  int*   gstart = (int*)w;   w += 1280;
  float* pooled = (float*)w; w += 262144;
  (void)ws_size; (void)n_in; (void)in_sizes; (void)out_size;

  cvt_f32_bf16<<<(N * 1280 / 4 + 255) / 256, 256, 0, stream>>>(x, XB, N * 1280 / 4);

  hipMemsetAsync(hist, 0, 80128, stream);
  hist_kernel<<<E / 256, 256, 0, stream>>>(ei + E, hist, E);
  scan_kernel<<<1, 1024, 0, stream>>>(hist, cursor, N, E);
  scatter_kernel<<<E / 256, 256, 0, stream>>>(ei, ei + E, ew, cursor, srcs, ews, E);

  bounds_kernel<<<1, 320, 0, stream>>>(batch, gstart, N);

  const unsigned short* in = XB;
  for (int l = 0; l < 4; l++){
    int K = Kd[l], Nf = Nd[l];
    int Nt = Nf / 128;
    wt_kernel<<<dim3(Nf / 32, K / 32), dim3(32, 8), 0, stream>>>(W[l], WT, K, Nf);
    gemm_bf16<<<157 * Nt, 256, 0, stream>>>(in, WT, H, Nf, K, Nt);
    if (Nf == 640)      agg_row<640><<<(N + 3) / 4, 256, 0, stream>>>(H, hist, srcs, ews, AGG, N);
    else if (Nf == 512) agg_row<512><<<(N + 3) / 4, 256, 0, stream>>>(H, hist, srcs, ews, AGG, N);
    else                agg_row<256><<<(N + 3) / 4, 256, 0, stream>>>(H, hist, srcs, ews, AGG, N);
    hipMemsetAsync(sum, 0, 5120, stream);
    stats_kernel_v<<<dim3((Nf / 4 + 255) / 256, 40), 256, 0, stream>>>(AGG, sum, sumsq, Nf);
    int total4 = N * (Nf >> 2);
    norm_kernel_v2<<<(total4 + 255) / 256, 256, 0, stream>>>(AGG, sum, sumsq, gw[l], bw[l], A1, Nf >> 2, total4);
    in = A1;
  }

  pool_kernel_v<<<256, 256, 0, stream>>>(A1, gstart, pooled);
  fc_kernel<<<256, 128, 0, stream>>>(pooled, Wf1, bf1, Wf2, bf2, Wf3, bf3, (float*)d_out);
}

// Round 10
// 769.203 us; speedup vs baseline: 1.0599x; 1.0152x over previous
//
#include <hip/hip_runtime.h>

typedef short bf16x8 __attribute__((ext_vector_type(8)));
typedef float f32x4  __attribute__((ext_vector_type(4)));

__device__ __forceinline__ float bf2f(unsigned short h){
  union { unsigned int u; float f; } c; c.u = ((unsigned int)h) << 16; return c.f;
}
__device__ __forceinline__ unsigned short f2bf(float f){
  union { float f; unsigned int u; } c; c.f = f;
  unsigned int u = c.u;
  return (unsigned short)((u + 0x7fffu + ((u >> 16) & 1u)) >> 16);
}
__device__ __forceinline__ void gload_lds16(const void* g, void* l){
  __builtin_amdgcn_global_load_lds((const __attribute__((address_space(1))) unsigned int*)g,
                                   (__attribute__((address_space(3))) unsigned int*)l, 16, 0, 0);
}
__device__ __forceinline__ float lrelu(float x){ return x >= 0.f ? x : 0.01f * x; }
// two bf16 packed in a dword -> two f32 fma into accumulators
__device__ __forceinline__ void acc2(float& a0, float& a1, unsigned int u, float w){
  float lo = __uint_as_float(u << 16);
  float hi = __uint_as_float(u & 0xffff0000u);
  a0 = fmaf(lo, w, a0); a1 = fmaf(hi, w, a1);
}

// ---------------- x (f32) -> bf16 ----------------
__global__ void cvt_f32_bf16(const float* __restrict__ x, unsigned short* __restrict__ o, int n4){
  int i = blockIdx.x * 256 + threadIdx.x;
  if (i >= n4) return;
  float4 v = ((const float4*)x)[i];
  ushort4 r; r.x = f2bf(v.x); r.y = f2bf(v.y); r.z = f2bf(v.z); r.w = f2bf(v.w);
  ((ushort4*)o)[i] = r;
}

// ---------------- W (K x N, f32) -> Wt (N x K, bf16) ----------------
__global__ void wt_kernel(const float* __restrict__ Wm, unsigned short* __restrict__ Wt, int K, int Nf){
  __shared__ float tile[32][33];
  int n0 = blockIdx.x * 32, k0 = blockIdx.y * 32;
  int tx = threadIdx.x, ty = threadIdx.y;
  for (int i = ty; i < 32; i += 8)
    tile[i][tx] = Wm[(size_t)(k0 + i) * Nf + n0 + tx];
  __syncthreads();
  for (int i = ty; i < 32; i += 8)
    Wt[(size_t)(n0 + i) * K + k0 + tx] = f2bf(tile[tx][i]);
}

// ---------------- counting sort of edges by dst ----------------
__global__ void hist_kernel(const int* __restrict__ dst, int* __restrict__ hist, int E){
  int e = blockIdx.x * 256 + threadIdx.x;
  if (e < E) atomicAdd(&hist[dst[e]], 1);
}

__global__ void scan_kernel(int* __restrict__ hist, int* __restrict__ cursor, int n, int total){
  __shared__ int partials[1024];
  const int CH = 20;
  int t = threadIdx.x;
  int base = t * CH;
  int local[CH];
  int s = 0;
  for (int i = 0; i < CH; i++){
    int idx = base + i;
    int v = (idx < n) ? hist[idx] : 0;
    local[i] = s; s += v;
  }
  partials[t] = s;
  __syncthreads();
  for (int off = 1; off < 1024; off <<= 1){
    int v = (t >= off) ? partials[t - off] : 0;
    __syncthreads();
    if (t >= off) partials[t] += v;
    __syncthreads();
  }
  int pre = (t == 0) ? 0 : partials[t - 1];
  for (int i = 0; i < CH; i++){
    int idx = base + i;
    if (idx < n){ int v = pre + local[i]; hist[idx] = v; cursor[idx] = v; }
  }
  if (t == 0){ hist[n] = total; }
}

__global__ void scatter_kernel(const int* __restrict__ src, const int* __restrict__ dst,
                               const float* __restrict__ ew, int* __restrict__ cursor,
                               int* __restrict__ so, float* __restrict__ eo, int E){
  int e = blockIdx.x * 256 + threadIdx.x;
  if (e >= E) return;
  int d = dst[e];
  int p = atomicAdd(&cursor[d], 1);
  so[p] = src[e]; eo[p] = ew[e];
}

// ---------------- GEMM: 128x128 tile, 4 waves, BK=32, double-buffered ----------------
// 2-phase pipeline: prefetch K-step t+1 via global_load_lds BEFORE ds_read+MFMA
// of step t; ONE barrier per step (its implicit vmcnt(0) drain overlaps compute).
// XOR chunk swizzle (both-sides): LDS slot (r, j) holds global chunk (r, j^(r&3));
// gload_lds dest stays LINEAR (slot = lane order), source addr pre-swizzled;
// ds_read uses chunk (c ^ (row&3)) -> banks spread 16-way -> ~2-way (free).
__global__ __launch_bounds__(256) void gemm_bf16(const unsigned short* __restrict__ A,
                                                 const unsigned short* __restrict__ Bt,
                                                 unsigned short* __restrict__ C,
                                                 int Nf, int K, int Nt){
  __shared__ unsigned short lsA[2][128 * 32];
  __shared__ unsigned short lsB[2][128 * 32];
  const int nwg = gridDim.x;
  const int orig = blockIdx.x;
  const int q = nwg >> 3, r = nwg & 7;
  const int xcd = orig & 7, idx = orig >> 3;
  const int wgid = (xcd < r ? xcd * (q + 1) : r * (q + 1) + (xcd - r) * q) + idx;
  const int mt = wgid / Nt, nt = wgid % Nt;

  const int tid = threadIdx.x;
  const int wave = tid >> 6, lane = tid & 63;
  const int wr = wave >> 1, wc = wave & 1;
  const size_t tm = (size_t)mt * 128, tn = (size_t)nt * 128;

  f32x4 acc[4][4] = {};

  // staging: slot s = tid (rows 0..63) and s = tid+256 (rows 64..127);
  // row = s>>2, phys chunk j = s&3, global col = k0 + (j ^ (row&3))*8
  const int srow = tid >> 2;
  const int co = (((tid & 3) ^ (srow & 3)) * 8);
  const unsigned short* Ab0 = A  + (tm + srow) * (size_t)K + co;
  const unsigned short* Ab1 = A  + (tm + 64 + srow) * (size_t)K + co;
  const unsigned short* Bb0 = Bt + (tn + srow) * (size_t)K + co;
  const unsigned short* Bb1 = Bt + (tn + 64 + srow) * (size_t)K + co;

  #define STAGE(b, k) {                                        \
    gload_lds16(Ab0 + (k), &lsA[b][tid * 8]);                  \
    gload_lds16(Ab1 + (k), &lsA[b][(tid + 256) * 8]);          \
    gload_lds16(Bb0 + (k), &lsB[b][tid * 8]);                  \
    gload_lds16(Bb1 + (k), &lsB[b][(tid + 256) * 8]);          \
  }

  STAGE(0, 0);
  __syncthreads();

  // reader: row = base + (lane&15); logical chunk c = lane>>4; swz = c ^ (row&3)
  const int rchunk = (((lane >> 4) ^ (lane & 3)) * 8);
  const int arow = wr * 64 + (lane & 15);
  const int brow = wc * 64 + (lane & 15);

  int cur = 0;
  for (int k0 = 0; k0 < K; k0 += 32){
    if (k0 + 32 < K) STAGE(cur ^ 1, k0 + 32);
    bf16x8 af[4], bfr[4];
    #pragma unroll
    for (int m = 0; m < 4; m++)
      af[m] = *(const bf16x8*)&lsA[cur][(arow + m * 16) * 32 + rchunk];
    #pragma unroll
    for (int n = 0; n < 4; n++)
      bfr[n] = *(const bf16x8*)&lsB[cur][(brow + n * 16) * 32 + rchunk];
    #pragma unroll
    for (int m = 0; m < 4; m++)
      #pragma unroll
      for (int n = 0; n < 4; n++)
        acc[m][n] = __builtin_amdgcn_mfma_f32_16x16x32_bf16(af[m], bfr[n], acc[m][n], 0, 0, 0);
    __syncthreads();
    cur ^= 1;
  }
  #undef STAGE

  #pragma unroll
  for (int m = 0; m < 4; m++)
    #pragma unroll
    for (int n = 0; n < 4; n++)
      #pragma unroll
      for (int j = 0; j < 4; j++){
        size_t row = tm + wr * 64 + m * 16 + (lane >> 4) * 4 + j;
        size_t col = tn + wc * 64 + n * 16 + (lane & 15);
        C[row * Nf + col] = f2bf(acc[m][n][j]);
      }
}

// ---------------- CSR aggregation: one WAVE per node, whole-row coalesced ----------------
template<int F>
__global__ __launch_bounds__(256)
void agg_row(const unsigned short* __restrict__ H,
             const int* __restrict__ rp,
             const int* __restrict__ srcs,
             const float* __restrict__ ews,
             float* __restrict__ AGG, int Nnodes){
  const int wv = threadIdx.x >> 6, ln = threadIdx.x & 63;
  int node = blockIdx.x * 4 + wv;
  if (node >= Nnodes) return;
  node = __builtin_amdgcn_readfirstlane(node);
  const int e0 = rp[node], e1 = rp[node + 1];
  const unsigned int* Hd = (const unsigned int*)H;
  constexpr int RD = F / 2;   // dwords per row

  float a0=0.f,a1=0.f,a2=0.f,a3=0.f,a4=0.f,a5=0.f,a6=0.f,a7=0.f,a8=0.f,a9=0.f;

  #define AGG_BODY(E) {                                            \
    int s_ = srcs[E]; float w_ = ews[E];                           \
    const unsigned int* row_ = Hd + (size_t)s_ * RD;               \
    if constexpr (F == 256){                                       \
      uint2 v_ = *(const uint2*)(row_ + ln * 2);                   \
      acc2(a0,a1,v_.x,w_); acc2(a2,a3,v_.y,w_);                    \
    } else if constexpr (F == 512){                                \
      uint4 v_ = *(const uint4*)(row_ + ln * 4);                   \
      acc2(a0,a1,v_.x,w_); acc2(a2,a3,v_.y,w_);                    \
      acc2(a4,a5,v_.z,w_); acc2(a6,a7,v_.w,w_);                    \
    } else {                                                       \
      uint4 v_ = *(const uint4*)(row_ + ln * 4);                   \
      unsigned int v2_ = row_[256 + ln];                           \
      acc2(a0,a1,v_.x,w_); acc2(a2,a3,v_.y,w_);                    \
      acc2(a4,a5,v_.z,w_); acc2(a6,a7,v_.w,w_);                    \
      acc2(a8,a9,v2_,w_);                                          \
    }                                                              \
  }

  int e = e0;
  for (; e + 1 < e1; e += 2){ AGG_BODY(e); AGG_BODY(e + 1); }
  if (e < e1) AGG_BODY(e);
  #undef AGG_BODY

  float* orow = AGG + (size_t)node * F;
  if constexpr (F == 256){
    float4 o = {a0, a1, a2, a3};
    *(float4*)(orow + ln * 4) = o;
  } else if constexpr (F == 512){
    float4 oA = {a0, a1, a2, a3}, oB = {a4, a5, a6, a7};
    *(float4*)(orow + ln * 8) = oA;
    *(float4*)(orow + ln * 8 + 4) = oB;
  } else {
    float4 oA = {a0, a1, a2, a3}, oB = {a4, a5, a6, a7};
    *(float4*)(orow + ln * 8) = oA;
    *(float4*)(orow + ln * 8 + 4) = oB;
    float2 oC = {a8, a9};
    *(float2*)(orow + 512 + ln * 2) = oC;
  }
}

// ---------------- column stats (float4) ----------------
__global__ void stats_kernel_v(const float* __restrict__ AGG, float* __restrict__ sum,
                               float* __restrict__ sumsq, int F){
  int nf4 = F >> 2;
  int f4 = blockIdx.x * 256 + threadIdx.x;
  if (f4 >= nf4) return;
  const float4* p = (const float4*)(AGG + (size_t)blockIdx.y * 500 * F) + f4;
  float4 s = {0.f,0.f,0.f,0.f}, q = {0.f,0.f,0.f,0.f};
  for (int r = 0; r < 500; r++){
    float4 v = p[(size_t)r * nf4];
    s.x += v.x; s.y += v.y; s.z += v.z; s.w += v.w;
    q.x += v.x*v.x; q.y += v.y*v.y; q.z += v.z*v.z; q.w += v.w*v.w;
  }
  atomicAdd(&sum[f4*4+0], s.x); atomicAdd(&sum[f4*4+1], s.y);
  atomicAdd(&sum[f4*4+2], s.z); atomicAdd(&sum[f4*4+3], s.w);
  atomicAdd(&sumsq[f4*4+0], q.x); atomicAdd(&sumsq[f4*4+1], q.y);
  atomicAdd(&sumsq[f4*4+2], q.z); atomicAdd(&sumsq[f4*4+3], q.w);
}

// ---------------- BN + LeakyReLU + cast, flat grid ----------------
__global__ void norm_kernel_v2(const float* __restrict__ AGG, const float* __restrict__ sum,
                               const float* __restrict__ sumsq, const float* __restrict__ gw,
                               const float* __restrict__ bw, unsigned short* __restrict__ OUT,
                               int nf4, int total4){
  int i = blockIdx.x * 256 + threadIdx.x;
  if (i >= total4) return;
  int f4 = i % nf4;
  const float inv = 1.0f / 20000.0f;
  float4 s = ((const float4*)sum)[f4];
  float4 q = ((const float4*)sumsq)[f4];
  float4 g = ((const float4*)gw)[f4];
  float4 b = ((const float4*)bw)[f4];
  float4 a = ((const float4*)AGG)[i];
  ushort4 o;
  { float m = s.x * inv, v = fmaxf(q.x * inv - m * m, 0.f);
    o.x = f2bf(lrelu((a.x - m) * rsqrtf(v + 1e-5f) * g.x + b.x)); }
  { float m = s.y * inv, v = fmaxf(q.y * inv - m * m, 0.f);
    o.y = f2bf(lrelu((a.y - m) * rsqrtf(v + 1e-5f) * g.y + b.y)); }
  { float m = s.z * inv, v = fmaxf(q.z * inv - m * m, 0.f);
    o.z = f2bf(lrelu((a.z - m) * rsqrtf(v + 1e-5f) * g.z + b.z)); }
  { float m = s.w * inv, v = fmaxf(q.w * inv - m * m, 0.f);
    o.w = f2bf(lrelu((a.w - m) * rsqrtf(v + 1e-5f) * g.w + b.w)); }
  ((ushort4*)OUT)[i] = o;
}

// ---------------- graph boundaries in sorted batch ----------------
__global__ void bounds_kernel(const int* __restrict__ batch, int* __restrict__ gstart, int n){
  int g = threadIdx.x;
  if (g > 256) return;
  int lo = 0, hi = n;
  while (lo < hi){ int mid = (lo + hi) >> 1; if (batch[mid] < g) lo = mid + 1; else hi = mid; }
  gstart[g] = lo;
}

// ---------------- pooling (vectorized) ----------------
__global__ __launch_bounds__(256) void pool_kernel_v(const unsigned short* __restrict__ A1,
                                                     const int* __restrict__ gstart,
                                                     float* __restrict__ pooled){
  int gph = blockIdx.x;
  int t = threadIdx.x;
  int c = t & 31, g = t >> 5;
  int r0 = gstart[gph], r1 = gstart[gph + 1];
  float acc[8] = {0.f,0.f,0.f,0.f,0.f,0.f,0.f,0.f};
  for (int r = r0 + g; r < r1; r += 8){
    bf16x8 v = *(const bf16x8*)&A1[(size_t)r * 256 + c * 8];
    #pragma unroll
    for (int j = 0; j < 8; j++) acc[j] += bf2f((unsigned short)v[j]);
  }
  __shared__ float red[8][256];
  if (g > 0){
    #pragma unroll
    for (int j = 0; j < 8; j++) red[g][c * 8 + j] = acc[j];
  }
  __syncthreads();
  if (g == 0){
    #pragma unroll
    for (int gg = 1; gg < 8; gg++)
      #pragma unroll
      for (int j = 0; j < 8; j++) acc[j] += red[gg][c * 8 + j];
    #pragma unroll
    for (int j = 0; j < 8; j++) pooled[gph * 256 + c * 8 + j] = acc[j];
  }
}

// ---------------- fused FC head: 256->128->64->2 with lrelu ----------------
__global__ void fc_kernel(const float* __restrict__ pooled,
                          const float* __restrict__ Wf1, const float* __restrict__ bf1,
                          const float* __restrict__ Wf2, const float* __restrict__ bf2,
                          const float* __restrict__ Wf3, const float* __restrict__ bf3,
                          float* __restrict__ out){
  int g = blockIdx.x, t = threadIdx.x; // 128 threads
  __shared__ float p0[256], p1[128], p2[64];
  p0[t] = pooled[g * 256 + t];
  p0[t + 128] = pooled[g * 256 + t + 128];
  __syncthreads();
  float a = bf1[t];
  for (int k = 0; k < 256; k++) a += p0[k] * Wf1[k * 128 + t];
  p1[t] = lrelu(a);
  __syncthreads();
  if (t < 64){
    float a2 = bf2[t];
    for (int k = 0; k < 128; k++) a2 += p1[k] * Wf2[k * 64 + t];
    p2[t] = lrelu(a2);
  }
  __syncthreads();
  if (t < 2){
    float a3 = bf3[t];
    for (int k = 0; k < 64; k++) a3 += p2[k] * Wf3[k * 2 + t];
    out[g * 2 + t] = lrelu(a3);
  }
}

extern "C" void kernel_launch(void* const* d_in, const int* in_sizes, int n_in,
                              void* d_out, int out_size, void* d_ws, size_t ws_size,
                              hipStream_t stream){
  const int N = 20000, E = 320000;
  const float* x     = (const float*)d_in[0];
  const int*   ei    = (const int*)d_in[1];
  const float* ew    = (const float*)d_in[2];
  const int*   batch = (const int*)d_in[3];
  const float* W[4]  = {(const float*)d_in[4], (const float*)d_in[8], (const float*)d_in[12], (const float*)d_in[16]};
  const float* gw[4] = {(const float*)d_in[6], (const float*)d_in[10], (const float*)d_in[14], (const float*)d_in[18]};
  const float* bw[4] = {(const float*)d_in[7], (const float*)d_in[11], (const float*)d_in[15], (const float*)d_in[19]};
  const float* Wf1 = (const float*)d_in[20]; const float* bf1 = (const float*)d_in[21];
  const float* Wf2 = (const float*)d_in[22]; const float* bf2 = (const float*)d_in[23];
  const float* Wf3 = (const float*)d_in[24]; const float* bf3 = (const float*)d_in[25];

  const int Kd[4] = {1280, 640, 512, 256};
  const int Nd[4] = {640, 512, 256, 256};

  // workspace carve (XB aliases AGG: XB dead after layer-1 GEMM)
  char* w = (char*)d_ws;
  unsigned short* XB = (unsigned short*)w;
  float* AGG = (float*)w;                 w += 51445760;  // 20096*1280*2
  unsigned short* H  = (unsigned short*)w; w += 25722880; // 20096*640*2
  unsigned short* A1 = (unsigned short*)w; w += 25722880; // 20096*640*2
  unsigned short* WT = (unsigned short*)w; w += 1638400;  // 1280*640*2
  int*   hist   = (int*)w;   w += 80128;  // 20001 ints (becomes row_ptr)
  int*   cursor = (int*)w;   w += 80128;
  int*   srcs   = (int*)w;   w += 1280000;
  float* ews    = (float*)w; w += 1280000;
  float* sum    = (float*)w; w += 2560;
  float* sumsq  = (float*)w; w += 2560;   // adjacent to sum: one memset
  int*   gstart = (int*)w;   w += 1280;
  float* pooled = (float*)w; w += 262144;
  (void)ws_size; (void)n_in; (void)in_sizes; (void)out_size;

  cvt_f32_bf16<<<(N * 1280 / 4 + 255) / 256, 256, 0, stream>>>(x, XB, N * 1280 / 4);

  hipMemsetAsync(hist, 0, 80128, stream);
  hist_kernel<<<E / 256, 256, 0, stream>>>(ei + E, hist, E);
  scan_kernel<<<1, 1024, 0, stream>>>(hist, cursor, N, E);
  scatter_kernel<<<E / 256, 256, 0, stream>>>(ei, ei + E, ew, cursor, srcs, ews, E);

  bounds_kernel<<<1, 320, 0, stream>>>(batch, gstart, N);

  const unsigned short* in = XB;
  for (int l = 0; l < 4; l++){
    int K = Kd[l], Nf = Nd[l];
    int Nt = Nf / 128;
    wt_kernel<<<dim3(Nf / 32, K / 32), dim3(32, 8), 0, stream>>>(W[l], WT, K, Nf);
    gemm_bf16<<<157 * Nt, 256, 0, stream>>>(in, WT, H, Nf, K, Nt);
    if (Nf == 640)      agg_row<640><<<(N + 3) / 4, 256, 0, stream>>>(H, hist, srcs, ews, AGG, N);
    else if (Nf == 512) agg_row<512><<<(N + 3) / 4, 256, 0, stream>>>(H, hist, srcs, ews, AGG, N);
    else                agg_row<256><<<(N + 3) / 4, 256, 0, stream>>>(H, hist, srcs, ews, AGG, N);
    hipMemsetAsync(sum, 0, 5120, stream);
    stats_kernel_v<<<dim3((Nf / 4 + 255) / 256, 40), 256, 0, stream>>>(AGG, sum, sumsq, Nf);
    int total4 = N * (Nf >> 2);
    norm_kernel_v2<<<(total4 + 255) / 256, 256, 0, stream>>>(AGG, sum, sumsq, gw[l], bw[l], A1, Nf >> 2, total4);
    in = A1;
  }

  pool_kernel_v<<<256, 256, 0, stream>>>(A1, gstart, pooled);
  fc_kernel<<<256, 128, 0, stream>>>(pooled, Wf1, bf1, Wf2, bf2, Wf3, bf3, (float*)d_out);
}